// Round 1
// 241.096 us; speedup vs baseline: 1.0514x; 1.0514x over previous
//
#include <hip/hip_runtime.h>
#include <hip/hip_bf16.h>

typedef unsigned short ushort_t;
typedef unsigned int uint_t;
typedef unsigned char uchar_t;

typedef __attribute__((ext_vector_type(8))) short bf16x8;
typedef __attribute__((ext_vector_type(4))) float f32x4;
typedef __attribute__((ext_vector_type(2))) float f32x2;

__device__ __forceinline__ float bf2f(ushort_t u) {
    union { uint_t i; float f; } v; v.i = ((uint_t)u) << 16; return v.f;
}
__device__ __forceinline__ ushort_t f2bf(float f) {
    __hip_bfloat16 h = __float2bfloat16(f);
    ushort_t u; __builtin_memcpy(&u, &h, 2); return u;
}
__device__ __forceinline__ uchar_t f2fp8(float v) {
    int p = __builtin_amdgcn_cvt_pk_fp8_f32(v, v, 0, false);
    return (uchar_t)(p & 0xff);
}
__device__ __forceinline__ float leaky(float v) { return (v > 0.f) ? v : 0.2f * v; }

#define PO_AS1 0
#define PO_AD1 512
#define PO_B1  1024
#define PO_W2  1536
#define PO_AS2 6656
#define PO_AD2 6666
#define PO_B2  6676
#define PTOT   6686

__device__ __forceinline__ bool detect_fp32_local(const ushort_t* __restrict__ xa) {
    __shared__ int cnt;
    if (threadIdx.x == 0) cnt = 0;
    __syncthreads();
    int bad = 0;
    for (int i = threadIdx.x; i < 4096; i += 256) {
        float v = bf2f(xa[i]);
        if (!(fabsf(v) < 1e4f)) bad++;
    }
    if (bad) atomicAdd(&cnt, bad);
    __syncthreads();
    return cnt >= 16;
}

// ---- prep: W1 transpose + param normalize + deg zero + gacc zero + dtype flag ----
__global__ __launch_bounds__(256) void k_prep(const void* __restrict__ x,
                                              const void* __restrict__ W1,
                                              const void* as1, const void* ad1,
                                              const void* b1, const void* W2,
                                              const void* as2, const void* ad2,
                                              const void* b2,
                                              ushort_t* __restrict__ W1t,
                                              float* __restrict__ prm,
                                              int* __restrict__ deg,
                                              float* __restrict__ gacc,
                                              int* __restrict__ flag, int N) {
    int b = blockIdx.x, t = threadIdx.x;
    if (b < 283) {
        bool isf = detect_fp32_local((const ushort_t*)x);
        if (b == 0 && t == 0) *flag = isf ? 1 : 0;
        if (b < 256) {
            int idx = b * 256 + t;
            int n = idx & 511, k = idx >> 9;
            float v = isf ? ((const float*)W1)[k * 512 + n]
                          : bf2f(((const ushort_t*)W1)[k * 512 + n]);
            W1t[n * 128 + k] = f2bf(v);
        } else {
            int i = (b - 256) * 256 + t;
            if (i < PTOT) {
                const void* src; int off;
                if (i < 512)       { src = as1; off = i; }
                else if (i < 1024) { src = ad1; off = i - 512; }
                else if (i < 1536) { src = b1;  off = i - 1024; }
                else if (i < 6656) { src = W2;  off = i - 1536; }
                else if (i < 6666) { src = as2; off = i - 6656; }
                else if (i < 6676) { src = ad2; off = i - 6666; }
                else               { src = b2;  off = i - 6676; }
                prm[i] = isf ? ((const float*)src)[off] : bf2f(((const ushort_t*)src)[off]);
            }
        }
    } else if (b < 362) {
        int i = (b - 283) * 256 + t;
        if (i < N) deg[i] = 0;
    } else {
        for (int i = t; i < 640; i += 256) gacc[i] = 0.f;
    }
}

// ------ fused GEMM1 (+logits) and degree histogram (unchanged) ------
__global__ __launch_bounds__(256) void k_gemm_hist(const void* __restrict__ xraw,
                                                   const ushort_t* __restrict__ w1t,
                                                   const float* __restrict__ prm,
                                                   const int* __restrict__ ei,
                                                   const int* __restrict__ flag,
                                                   uchar_t* __restrict__ h1,
                                                   float* __restrict__ asrcf,
                                                   float* __restrict__ adstf,
                                                   int* __restrict__ deg,
                                                   int E, int Etot) {
    int b = blockIdx.x, t = threadIdx.x;
    if (b >= 1250) {
        int e = (b - 1250) * 256 + t;
        if (e < Etot) {
            int dst = (e < E) ? ei[E + e] : (e - E);
            atomicAdd(&deg[dst], 1);
        }
        return;
    }
    int wave = t >> 6, lane = t & 63;
    int m0 = b * 16;
    bool isf = (*flag != 0);
    __shared__ ushort_t sA[16 * 128];
    {
        ushort_t tmp[8];
        if (isf) {
            const float4* x4 = (const float4*)((const float*)xraw + (size_t)m0 * 128);
            float4 f0 = x4[2 * t], f1 = x4[2 * t + 1];
            tmp[0] = f2bf(f0.x); tmp[1] = f2bf(f0.y); tmp[2] = f2bf(f0.z); tmp[3] = f2bf(f0.w);
            tmp[4] = f2bf(f1.x); tmp[5] = f2bf(f1.y); tmp[6] = f2bf(f1.z); tmp[7] = f2bf(f1.w);
        } else {
            const uint4* x4 = (const uint4*)((const ushort_t*)xraw + (size_t)m0 * 128);
            uint4 u = x4[t];
            __builtin_memcpy(tmp, &u, 16);
        }
        *reinterpret_cast<uint4*>(&sA[t * 8]) = *reinterpret_cast<uint4*>(tmp);
    }
    __syncthreads();
    int mr = lane & 15, quad = lane >> 4;
    int n0 = wave * 128;
    f32x4 acc[8];
#pragma unroll
    for (int ct = 0; ct < 8; ++ct) acc[ct] = {0.f, 0.f, 0.f, 0.f};
#pragma unroll
    for (int kk = 0; kk < 4; ++kk) {
        bf16x8 a = *reinterpret_cast<const bf16x8*>(&sA[mr * 128 + quad * 8 + kk * 32]);
#pragma unroll
        for (int ct = 0; ct < 8; ++ct) {
            bf16x8 bb = *reinterpret_cast<const bf16x8*>(
                &w1t[(size_t)(n0 + ct * 16 + mr) * 128 + quad * 8 + kk * 32]);
            acc[ct] = __builtin_amdgcn_mfma_f32_16x16x32_bf16(a, bb, acc[ct], 0, 0, 0);
        }
    }
    int col = lane & 15;
#pragma unroll
    for (int hh = 0; hh < 2; ++hh) {
        float ps[4] = {0.f, 0.f, 0.f, 0.f}, pd[4] = {0.f, 0.f, 0.f, 0.f};
#pragma unroll
        for (int c4 = 0; c4 < 4; ++c4) {
            int ct = hh * 4 + c4;
            int abscol = n0 + ct * 16 + col;
            float asv = prm[PO_AS1 + abscol];
            float adv = prm[PO_AD1 + abscol];
#pragma unroll
            for (int r = 0; r < 4; ++r) {
                h1[(size_t)(m0 + quad * 4 + r) * 512 + abscol] = f2fp8(acc[ct][r]);
                ps[r] += acc[ct][r] * asv;
                pd[r] += acc[ct][r] * adv;
            }
        }
#pragma unroll
        for (int off = 1; off <= 8; off <<= 1) {
#pragma unroll
            for (int r = 0; r < 4; ++r) {
                ps[r] += __shfl_xor(ps[r], off, 64);
                pd[r] += __shfl_xor(pd[r], off, 64);
            }
        }
        if (col == 0) {
            int head = 2 * wave + hh;
#pragma unroll
            for (int r = 0; r < 4; ++r) {
                asrcf[(m0 + quad * 4 + r) * 8 + head] = ps[r];
                adstf[(m0 + quad * 4 + r) * 8 + head] = pd[r];
            }
        }
    }
}

// ---- single-kernel exclusive scan (unchanged) ----
__global__ __launch_bounds__(256) void k_scan(const int* __restrict__ deg,
                                              int* __restrict__ rowptr,
                                              int* __restrict__ cursor, int N) {
    int b = blockIdx.x, t = threadIdx.x;
    int lane = t & 63, wv = t >> 6;
    __shared__ int ws[4], wt[4];
    __shared__ int sbase;
    int limit = b * 256;
    int partial = 0;
    for (int i = t; i < limit; i += 256) partial += deg[i];
#pragma unroll
    for (int off = 32; off; off >>= 1) partial += __shfl_xor(partial, off, 64);
    if (lane == 0) ws[wv] = partial;
    __syncthreads();
    if (t == 0) sbase = ws[0] + ws[1] + ws[2] + ws[3];
    __syncthreads();
    int base = sbase;
    int i = limit + t;
    int v = (i < N) ? deg[i] : 0;
    int inc = v;
#pragma unroll
    for (int off = 1; off < 64; off <<= 1) {
        int u = __shfl_up(inc, off, 64);
        if (lane >= off) inc += u;
    }
    if (lane == 63) wt[wv] = inc;
    __syncthreads();
    int woff = 0;
    for (int w = 0; w < 4; ++w) if (w < wv) woff += wt[w];
    int excl = base + woff + inc - v;
    if (i < N) { rowptr[i + 1] = excl + v; cursor[i] = excl; }
    if (i == 0) rowptr[0] = 0;
}

// ---- scatter + PRECOMPUTE per-edge softmax weights (8 heads, csr-ordered) ----
// Moves the dependent {scattered asrcf/adstf gather + leaky + exp} OFF k_agg1's
// critical chain into a fully thread-parallel pass where latency is trivially hidden.
__global__ __launch_bounds__(256) void k_scatter(const int* __restrict__ ei,
                                                 int* __restrict__ cursor,
                                                 const float* __restrict__ asrcf,
                                                 const float* __restrict__ adstf,
                                                 int* __restrict__ csr_src,
                                                 float* __restrict__ wcsr,
                                                 int E, int Etot) {
    int e = blockIdx.x * 256 + threadIdx.x;
    if (e >= Etot) return;
    int src, dst;
    if (e < E) { src = ei[e]; dst = ei[E + e]; } else { src = dst = e - E; }
    int pos = atomicAdd(&cursor[dst], 1);
    csr_src[pos] = src;
    const float4* ap = (const float4*)&asrcf[(size_t)src * 8];
    const float4* bp = (const float4*)&adstf[(size_t)dst * 8];
    float4 a0 = ap[0], a1 = ap[1];
    float4 b0 = bp[0], b1 = bp[1];
    float4 w0, w1;
    w0.x = __expf(leaky(a0.x + b0.x));
    w0.y = __expf(leaky(a0.y + b0.y));
    w0.z = __expf(leaky(a0.z + b0.z));
    w0.w = __expf(leaky(a0.w + b0.w));
    w1.x = __expf(leaky(a1.x + b1.x));
    w1.y = __expf(leaky(a1.y + b1.y));
    w1.z = __expf(leaky(a1.z + b1.z));
    w1.w = __expf(leaky(a1.w + b1.w));
    float4* wp = (float4*)&wcsr[(size_t)pos * 8];
    wp[0] = w0; wp[1] = w1;
}

// --- layer-1 agg + ELU + layer-2 linear&logits. TWO waves per node (edge-split),
// weights precomputed (streamed from wcsr) -> inner loop is pure gather+FMA. ---
__global__ __launch_bounds__(256) void k_agg1(const uchar_t* __restrict__ h1,
                                              const int* __restrict__ rowptr,
                                              const int* __restrict__ csr_src,
                                              const float* __restrict__ wcsr,
                                              const float* __restrict__ prm,
                                              float* __restrict__ h2,
                                              float* __restrict__ asrc2f,
                                              float* __restrict__ adst2f) {
    int wid = threadIdx.x >> 6;
    int ni = wid >> 1;          // node slot in block (0..1)
    int half = wid & 1;         // edge-range half
    int n = blockIdx.x * 2 + ni;
    int lane = threadIdx.x & 63;
    int hh = lane >> 3;
    int cb = lane * 8;
    int start = rowptr[n], end = rowptr[n + 1];
    int deg = end - start;
    int mid = (deg + 1) >> 1;
    int es = start + (half ? mid : 0);
    int ee = half ? end : (start + mid);
    float a0 = 0.f, a1 = 0.f, a2 = 0.f, a3 = 0.f, a4 = 0.f, a5 = 0.f, a6 = 0.f, a7 = 0.f;
    float den = 0.f;
    for (int base = es; base < ee; base += 64) {
        int m = min(64, ee - base);
        int sIdx = csr_src[base + min(lane, m - 1)];
        for (int g = 0; g < m; g += 8) {
            int s[8]; float w[8]; uint2 p[8];
#pragma unroll
            for (int j = 0; j < 8; ++j)
                s[j] = __shfl(sIdx, min(g + j, m - 1), 64);
#pragma unroll
            for (int j = 0; j < 8; ++j)
                w[j] = wcsr[(size_t)(base + min(g + j, m - 1)) * 8 + hh];
#pragma unroll
            for (int j = 0; j < 8; ++j)
                p[j] = *reinterpret_cast<const uint2*>(&h1[(size_t)s[j] * 512 + cb]);
#pragma unroll
            for (int j = 0; j < 8; ++j) {
                float we = (g + j < m) ? w[j] : 0.f;
                den += we;
                f32x2 q0 = __builtin_amdgcn_cvt_pk_f32_fp8((int)p[j].x, false);
                f32x2 q1 = __builtin_amdgcn_cvt_pk_f32_fp8((int)p[j].x, true);
                f32x2 q2 = __builtin_amdgcn_cvt_pk_f32_fp8((int)p[j].y, false);
                f32x2 q3 = __builtin_amdgcn_cvt_pk_f32_fp8((int)p[j].y, true);
                a0 += we * q0.x; a1 += we * q0.y;
                a2 += we * q1.x; a3 += we * q1.y;
                a4 += we * q2.x; a5 += we * q2.y;
                a6 += we * q3.x; a7 += we * q3.y;
            }
        }
    }
    __shared__ float sred[2][64][9];  // stride 9 (odd) -> bank-conflict-free
    if (half) {
        float* sp = sred[ni][lane];
        sp[0] = a0; sp[1] = a1; sp[2] = a2; sp[3] = a3;
        sp[4] = a4; sp[5] = a5; sp[6] = a6; sp[7] = a7; sp[8] = den;
    }
    __syncthreads();
    if (half) return;
    {
        const float* sp = sred[ni][lane];
        a0 += sp[0]; a1 += sp[1]; a2 += sp[2]; a3 += sp[3];
        a4 += sp[4]; a5 += sp[5]; a6 += sp[6]; a7 += sp[7]; den += sp[8];
    }
    float inv = 1.f / (den + 1e-16f);
    float r[8] = {a0, a1, a2, a3, a4, a5, a6, a7};
    float p2[10];
#pragma unroll
    for (int c = 0; c < 10; ++c) p2[c] = 0.f;
#pragma unroll
    for (int j = 0; j < 8; ++j) {
        float rv = r[j] * inv + prm[PO_B1 + cb + j];
        rv = (rv > 0.f) ? rv : expm1f(rv);    // ELU
#pragma unroll
        for (int c = 0; c < 10; ++c)
            p2[c] += rv * prm[PO_W2 + (cb + j) * 10 + c];
    }
#pragma unroll
    for (int c = 0; c < 10; ++c)
#pragma unroll
        for (int off = 32; off; off >>= 1)
            p2[c] += __shfl_xor(p2[c], off, 64);
    if (lane == 0) {
        float as = 0.f, ad = 0.f;
#pragma unroll
        for (int c = 0; c < 10; ++c) {
            h2[(size_t)n * 16 + c] = p2[c];   // 64B-padded rows: 1 cache line/gather
            as += p2[c] * prm[PO_AS2 + c];
            ad += p2[c] * prm[PO_AD2 + c];
        }
        asrc2f[n] = as; adst2f[n] = ad;
    }
}

// ------- layer-2 softmax+agg, 16 LANES PER NODE (deg~17 -> ~full lane util),
// fused mean-pool via sorted-batch run compaction + few atomics -------
__global__ __launch_bounds__(256) void k_agg2(const float* __restrict__ h2,
                                              const float* __restrict__ asrc2f,
                                              const float* __restrict__ adst2f,
                                              const int* __restrict__ rowptr,
                                              const int* __restrict__ csr_src,
                                              const float* __restrict__ prm,
                                              const int* __restrict__ batch,
                                              float* __restrict__ gacc) {
    int t = threadIdx.x;
    int grp = t >> 4, l = t & 15;
    int n = blockIdx.x * 16 + grp;
    int start = rowptr[n], end = rowptr[n + 1];
    float adn = adst2f[n];
    float den = 0.f;
    float oc[10];
#pragma unroll
    for (int c = 0; c < 10; ++c) oc[c] = 0.f;
    for (int e = start + l; e < end; e += 16) {
        int s = csr_src[e];
        float lo = asrc2f[s];
        const float4* hp = reinterpret_cast<const float4*>(&h2[(size_t)s * 16]);
        float4 q0 = hp[0], q1 = hp[1];
        float2 q2 = *reinterpret_cast<const float2*>(&h2[(size_t)s * 16 + 8]);
        float ee = __expf(leaky(lo + adn));
        den += ee;
        oc[0] += ee * q0.x; oc[1] += ee * q0.y; oc[2] += ee * q0.z; oc[3] += ee * q0.w;
        oc[4] += ee * q1.x; oc[5] += ee * q1.y; oc[6] += ee * q1.z; oc[7] += ee * q1.w;
        oc[8] += ee * q2.x; oc[9] += ee * q2.y;
    }
#pragma unroll
    for (int off = 8; off; off >>= 1) {
        den += __shfl_xor(den, off, 64);
#pragma unroll
        for (int c = 0; c < 10; ++c) oc[c] += __shfl_xor(oc[c], off, 64);
    }
    __shared__ float sres[16][11];
    __shared__ int sg[16];
    if (l == 0) {
        float invd = 1.f / (den + 1e-16f);
#pragma unroll
        for (int c = 0; c < 10; ++c) sres[grp][c] = oc[c] * invd + prm[PO_B2 + c];
        sg[grp] = batch[n];
    }
    __syncthreads();
    // batch is sorted -> few distinct graphs per block; flush runs with 1 atomic each
    if (t < 10) {
        int c = t;
        float run = sres[0][c]; int g = sg[0];
        for (int k = 1; k < 16; ++k) {
            if (sg[k] != g) {
                atomicAdd(&gacc[g * 10 + c], run);
                g = sg[k]; run = 0.f;
            }
            run += sres[k][c];
        }
        atomicAdd(&gacc[g * 10 + c], run);
    }
}

// ---------------- final divide + dtype-flagged output ----------------
__global__ void k_final(const float* __restrict__ gacc,
                        const int* __restrict__ batch,
                        const int* __restrict__ flag,
                        void* __restrict__ dout, int N) {
    int g = threadIdx.x;
    if (g >= 64) return;
    bool isf = (*flag != 0);
    int lo = 0, hi = N;
    while (lo < hi) { int mid = (lo + hi) >> 1; if (batch[mid] < g) lo = mid + 1; else hi = mid; }
    int lo2 = lo, hi2 = N;
    while (lo2 < hi2) { int mid = (lo2 + hi2) >> 1; if (batch[mid] < g + 1) lo2 = mid + 1; else hi2 = mid; }
    int count = lo2 - lo;
    float cnt = (float)(count > 0 ? count : 1);
    for (int c = 0; c < 10; ++c) {
        float r = gacc[g * 10 + c] / cnt;
        if (isf) ((float*)dout)[g * 10 + c] = r;
        else     ((ushort_t*)dout)[g * 10 + c] = f2bf(r);
    }
}

extern "C" void kernel_launch(void* const* d_in, const int* in_sizes, int n_in,
                              void* d_out, int out_size, void* d_ws, size_t ws_size,
                              hipStream_t stream) {
    const void* x   = d_in[0];
    const int* ei   = (const int*)d_in[1];
    const int* batch= (const int*)d_in[2];
    const void* W1  = d_in[3];
    const void* as1 = d_in[4];
    const void* ad1 = d_in[5];
    const void* b1  = d_in[6];
    const void* W2  = d_in[7];
    const void* as2 = d_in[8];
    const void* ad2 = d_in[9];
    const void* b2  = d_in[10];

    constexpr int N = 20000, E = 320000, Etot = E + N;
    constexpr int histBlocks = (Etot + 255) / 256;

    char* p = (char*)d_ws;
    auto alloc = [&](size_t bytes) {
        char* r = p; p += (bytes + 255) & ~(size_t)255; return r;
    };
    int* flag       = (int*)alloc(256);
    float* prm      = (float*)alloc((size_t)PTOT * 4);
    ushort_t* w1t   = (ushort_t*)alloc(512 * 128 * 2);
    uchar_t* h1     = (uchar_t*)alloc((size_t)N * 512);           // 10.24 MB fp8
    float* asrc1f   = (float*)alloc((size_t)N * 8 * 4);
    float* adst1f   = (float*)alloc((size_t)N * 8 * 4);
    float* asrc2f   = (float*)alloc((size_t)N * 4);
    float* adst2f   = (float*)alloc((size_t)N * 4);
    float* h2       = (float*)alloc((size_t)N * 16 * 4);          // 64B padded rows
    float* gacc     = (float*)alloc((size_t)64 * 10 * 4);
    int* deg        = (int*)alloc((size_t)N * 4);
    int* rowptr     = (int*)alloc((size_t)(N + 1) * 4);
    int* cursor     = (int*)alloc((size_t)N * 4);
    int* csr_src    = (int*)alloc((size_t)Etot * 4);
    float* wcsr     = (float*)alloc((size_t)Etot * 8 * 4);        // 10.88 MB weights

    k_prep<<<363, 256, 0, stream>>>(x, W1, as1, ad1, b1, W2, as2, ad2, b2,
                                    w1t, prm, deg, gacc, flag, N);
    k_gemm_hist<<<1250 + histBlocks, 256, 0, stream>>>(x, w1t, prm, ei, flag, h1,
                                                       asrc1f, adst1f, deg, E, Etot);
    k_scan<<<(N + 255) / 256, 256, 0, stream>>>(deg, rowptr, cursor, N);
    k_scatter<<<histBlocks, 256, 0, stream>>>(ei, cursor, asrc1f, adst1f,
                                              csr_src, wcsr, E, Etot);
    k_agg1<<<N / 2, 256, 0, stream>>>(h1, rowptr, csr_src, wcsr, prm,
                                      h2, asrc2f, adst2f);
    k_agg2<<<N / 16, 256, 0, stream>>>(h2, asrc2f, adst2f, rowptr, csr_src, prm,
                                       batch, gacc);
    k_final<<<1, 64, 0, stream>>>(gacc, batch, flag, d_out, N);
}